// Round 32
// baseline (330.236 us; speedup 1.0000x reference)
//
#include <hip/hip_runtime.h>
#include <math.h>

#define NA 8000
#define NV 4000
#define NN 12000
#define NA_PAD 8192
#define NV_PAD 4096
#define KNN_TILE 1024
#define FEAT 32
#define HD 64
#define NLAYER 12
#define E_AA 80000
#define E_AV 120000
#define E_VV 60000
#define E_TOT 260000
#define ENC_SIZE (NV * HD)
#define EPS 1e-5f
#define NGRP (NN/4)
#define KNN_BLOCKS (NA/8 + NA/8 + NV/8)   // 2500
#define INIT_BLOCKS (NN/8)                 // 1500

__device__ __forceinline__ float wave_sum64(float v) {
#pragma unroll
  for (int off = 1; off < 64; off <<= 1) v += __shfl_xor(v, off);
  return v;
}

// DPP butterfly helpers: pure VALU (v_add_f32_dpp), no DS pipe.
__device__ __forceinline__ float dpp_step(float v, const int ctrl) {
  int p;
  switch (ctrl) {
    case 0xB1:  p = __builtin_amdgcn_update_dpp(0, __float_as_int(v), 0xB1,  0xF, 0xF, true); break;
    case 0x4E:  p = __builtin_amdgcn_update_dpp(0, __float_as_int(v), 0x4E,  0xF, 0xF, true); break;
    case 0x141: p = __builtin_amdgcn_update_dpp(0, __float_as_int(v), 0x141, 0xF, 0xF, true); break;
    default:    p = __builtin_amdgcn_update_dpp(0, __float_as_int(v), 0x140, 0xF, 0xF, true); break;
  }
  return v + __int_as_float(p);
}

__device__ __forceinline__ float head_sum16_dpp(float v) {
  v = dpp_step(v, 0xB1);
  v = dpp_step(v, 0x4E);
  v = dpp_step(v, 0x141);
  v = dpp_step(v, 0x140);
  return v;
}

__device__ __forceinline__ float wave_sum64_dpp(float v) {
  v = head_sum16_dpp(v);
  v += __shfl_xor(v, 16);
  v += __shfl_xor(v, 32);
  return v;
}

// DPP wave_shr:1 (ctrl 0x138): pure-VALU __shfl_up(x,1); lane-0 shifted
// values are dead in the insert (pS forced to 1). (r27, passing)
__device__ __forceinline__ float dpp_shr1_f(float v) {
  const int p = __builtin_amdgcn_update_dpp(0, __float_as_int(v), 0x138, 0xF, 0xF, true);
  return __int_as_float(p);
}
__device__ __forceinline__ int dpp_shr1_i(int v) {
  return __builtin_amdgcn_update_dpp(0, v, 0x138, 0xF, 0xF, true);
}

// ---------------------------------------------------------------------------
// Pack candidate positions as [x, y, z, |c|^2] float4, padded with cc=+INF.
// (FROZEN)
// ---------------------------------------------------------------------------
__global__ __launch_bounds__(256) void pack_kernel(
    const float* __restrict__ apos, const float* __restrict__ vpos,
    float4* __restrict__ apk, float4* __restrict__ vpk)
{
  const int i = blockIdx.x * 256 + threadIdx.x;
  if (i < NA_PAD) {
    float4 r;
    if (i < NA) {
      const float cx = apos[i*3+0], cy = apos[i*3+1], cz = apos[i*3+2];
      r = make_float4(cx, cy, cz, (cx*cx + cy*cy) + cz*cz);
    } else r = make_float4(0.f, 0.f, 0.f, INFINITY);
    apk[i] = r;
  } else {
    const int j = i - NA_PAD;
    if (j < NV_PAD) {
      float4 r;
      if (j < NV) {
        const float cx = vpos[j*3+0], cy = vpos[j*3+1], cz = vpos[j*3+2];
        r = make_float4(cx, cy, cz, (cx*cx + cy*cy) + cz*cz);
      } else r = make_float4(0.f, 0.f, 0.f, INFINITY);
      vpk[j] = r;
    }
  }
}

// ---------------------------------------------------------------------------
// Batched brute-force kNN (r26-r28, passing, FROZEN): pinned d2, DPP insert,
// double-buffered staging, ONE query per wave.
// ---------------------------------------------------------------------------
#define KNN_INS(D2, JB)                                                \
  {                                                                    \
    unsigned long long m = __ballot((D2) < thrD);                      \
    if (m) {                                                           \
      do {                                                             \
        const int sl = __ffsll(m) - 1;                                 \
        m &= (m - 1ULL);                                               \
        const float v  = __shfl((D2), sl);                             \
        const int   vi = (JB) + sl;                                    \
        const bool stay = (eD < v) || (eD == v && eI < vi);            \
        const float pD = dpp_shr1_f(eD);                               \
        const int   pI = dpp_shr1_i(eI);                               \
        int pS = dpp_shr1_i(stay ? 1 : 0);                             \
        if (lane == 0) pS = 1;                                         \
        eD = stay ? eD : (pS ? v  : pD);                               \
        eI = stay ? eI : (pS ? vi : pI);                               \
      } while (m);                                                     \
      thrD = __shfl(eD, K-1);                                          \
    }                                                                  \
  }

template<int K, int NC_PAD>
__device__ __attribute__((noinline)) void knn_body(
    const float* __restrict__ qpos, const float4* __restrict__ cpk,
    int c_off, int* __restrict__ out_src, int qblock)
{
  extern __shared__ float4 tile[];            // [2][KNN_TILE]
  const int tid  = threadIdx.x;
  const int wid  = tid >> 6, lane = tid & 63;
  const int q    = qblock * 8 + wid;
  const float qx = qpos[q*3+0], qy = qpos[q*3+1], qz = qpos[q*3+2];
  float qt = __fmul_rn(qx, qx);
  qt = __fmaf_rn(qy, qy, qt);
  const float qq = __fmaf_rn(qz, qz, qt);     // pinned (r23-verified seq)

  float eD = INFINITY; int eI = 0x7fffffff;   // this lane's entry of the list
  float thrD = INFINITY;                       // K-th best (broadcast)

  // prologue: stage tile 0 into buffer 0
#pragma unroll
  for (int s = 0; s < KNN_TILE/512; ++s)
    tile[s*512 + tid] = cpk[s*512 + tid];
  __syncthreads();

  int cur = 0;
  for (int t0 = 0; t0 < NC_PAD; t0 += KNN_TILE) {
    const int t1 = t0 + KNN_TILE;
    if (t1 < NC_PAD) {                         // stage next tile into other buf
#pragma unroll
      for (int s = 0; s < KNN_TILE/512; ++s)
        tile[(cur^1)*KNN_TILE + s*512 + tid] = cpk[t1 + s*512 + tid];
    }
    const float4* tb = tile + cur*KNN_TILE;
#pragma unroll
    for (int it = 0; it < KNN_TILE/256; ++it) {
      const int b = it*256;
      const float4 c0 = tb[b +   0 + lane];
      const float4 c1 = tb[b +  64 + lane];
      const float4 c2 = tb[b + 128 + lane];
      const float4 c3 = tb[b + 192 + lane];
      float u0 = __fmul_rn(qx, c0.x); u0 = __fmaf_rn(qy, c0.y, u0);
      const float dot0 = __fmaf_rn(qz, c0.z, u0);
      const float d20  = __fadd_rn(__fmaf_rn(-2.0f, dot0, qq), c0.w);
      float u1 = __fmul_rn(qx, c1.x); u1 = __fmaf_rn(qy, c1.y, u1);
      const float dot1 = __fmaf_rn(qz, c1.z, u1);
      const float d21  = __fadd_rn(__fmaf_rn(-2.0f, dot1, qq), c1.w);
      float u2 = __fmul_rn(qx, c2.x); u2 = __fmaf_rn(qy, c2.y, u2);
      const float dot2 = __fmaf_rn(qz, c2.z, u2);
      const float d22  = __fadd_rn(__fmaf_rn(-2.0f, dot2, qq), c2.w);
      float u3 = __fmul_rn(qx, c3.x); u3 = __fmaf_rn(qy, c3.y, u3);
      const float dot3 = __fmaf_rn(qz, c3.z, u3);
      const float d23  = __fadd_rn(__fmaf_rn(-2.0f, dot3, qq), c3.w);
      const float dmin = fminf(fminf(d20, d21), fminf(d22, d23));
      if (__ballot(dmin < thrD)) {             // no lane qualifies -> no insert
        KNN_INS(d20, t0 + b +   0)
        KNN_INS(d21, t0 + b +  64)
        KNN_INS(d22, t0 + b + 128)
        KNN_INS(d23, t0 + b + 192)
      }
    }
    __syncthreads();                           // next tile staged, cur consumed
    cur ^= 1;
  }
  if (lane < K) out_src[q*K + lane] = eI + c_off;
}

// ---------------------------------------------------------------------------
// LayerNorm + s/d projection, single-wave version (used by init branch).
// ---------------------------------------------------------------------------
__device__ __forceinline__ void ln_sd(
    float v, int node, int lane, int l,
    const float* __restrict__ ln_g, const float* __restrict__ ln_b,
    const float* __restrict__ Ws, const float* __restrict__ Wd,
    float* __restrict__ sbuf, float* __restrict__ dbuf)
{
  const float m = wave_sum64_dpp(v) * (1.0f/64.0f);
  const float c = v - m;
  const float var = wave_sum64_dpp(c*c) * (1.0f/64.0f);
  const float hn = c * rsqrtf(var + EPS) * ln_g[l*HD + lane] + ln_b[l*HD + lane];
  const float* ws = Ws + (size_t)l*HD*HD;
  const float* wd = Wd + (size_t)l*HD*HD;
  float accs = 0.0f, accd = 0.0f;
#pragma unroll
  for (int j = 0; j < HD; ++j) {
    const float hj = __shfl(hn, j);
    accs += hj * ws[j*HD + lane];
    accd += hj * wd[j*HD + lane];
  }
  sbuf[node*HD + lane] = accs;
  dbuf[node*HD + lane] = accd;
}

// init work for one node (verbatim init arithmetic; one wave per node).
__device__ __forceinline__ void init_node(
    int node, int lane,
    const float* __restrict__ atom_x, const float* __restrict__ vox_x,
    const float* __restrict__ Wa, const float* __restrict__ ba,
    const float* __restrict__ Wv, const float* __restrict__ bv,
    const float* __restrict__ ln_g, const float* __restrict__ ln_b,
    const float* __restrict__ Ws, const float* __restrict__ Wd,
    float* __restrict__ x, float* __restrict__ snap0,
    float* __restrict__ sbuf, float* __restrict__ dbuf)
{
  const float* in; const float* W; const float* b;
  if (node < NA) { in = atom_x + node*FEAT;     W = Wa; b = ba; }
  else           { in = vox_x + (node-NA)*FEAT; W = Wv; b = bv; }
  float acc = b[lane];
#pragma unroll
  for (int j = 0; j < FEAT; ++j) acc += in[j] * W[j*HD + lane];
  x[node*HD + lane] = acc;
  if (node >= NA) snap0[(node-NA)*HD + lane] = acc;
  ln_sd(acc, node, lane, 0, ln_g, ln_b, Ws, Wd, sbuf, dbuf);
}

// Merged dispatcher: 3 kNN scans + init (independent work) co-resident.
__global__ __launch_bounds__(512) void knn_all_kernel(
    const float* __restrict__ apos, const float* __restrict__ vpos,
    const float4* __restrict__ apk, const float4* __restrict__ vpk,
    int* __restrict__ srcA, int* __restrict__ srcAV, int* __restrict__ srcVV,
    const float* __restrict__ atom_x, const float* __restrict__ vox_x,
    const float* __restrict__ Wa, const float* __restrict__ ba,
    const float* __restrict__ Wv, const float* __restrict__ bv,
    const float* __restrict__ ln_g, const float* __restrict__ ln_b,
    const float* __restrict__ Ws, const float* __restrict__ Wd,
    float* __restrict__ x, float* __restrict__ snap0,
    float* __restrict__ sbuf0, float* __restrict__ dbuf)
{
  const int b = blockIdx.x;                   // block-uniform branch
  const int wid = threadIdx.x >> 6, lane = threadIdx.x & 63;
  if (b < NA/8)
    knn_body<10, NA_PAD>(apos, apk, 0,  srcA,  b);
  else if (b < 2*(NA/8))
    knn_body<15, NV_PAD>(apos, vpk, NA, srcAV, b - NA/8);
  else if (b < KNN_BLOCKS)
    knn_body<15, NV_PAD>(vpos, vpk, NA, srcVV, b - 2*(NA/8));
  else {
    const int node = (b - KNN_BLOCKS)*8 + wid;   // 1500 blocks x 8 = NN
    init_node(node, lane, atom_x, vox_x, Wa, ba, Wv, bv,
              ln_g, ln_b, Ws, Wd, x, snap0, sbuf0, dbuf);
  }
}

// ---------------------------------------------------------------------------
// Edge attribute MLP.
// ---------------------------------------------------------------------------
__device__ __forceinline__ void load_pos(const float* ap, const float* vp,
                                         int i, float& px, float& py, float& pz)
{
  const float* p = (i < NA) ? (ap + i*3) : (vp + (i - NA)*3);
  px = p[0]; py = p[1]; pz = p[2];
}

__global__ __launch_bounds__(256) void edge_attr_kernel(
    const float* __restrict__ atom_pos, const float* __restrict__ vox_pos,
    const int* __restrict__ srcA, const int* __restrict__ srcAV,
    const int* __restrict__ srcVV,
    const float* __restrict__ w1, const float* __restrict__ b1,
    const float* __restrict__ w2, const float* __restrict__ b2,
    float* __restrict__ eattr)
{
  const int e = blockIdx.x * 256 + threadIdx.x;
  if (e >= E_TOT) return;
  int s, d, mi;
  if (e < E_AA)              { mi = 0; s = srcA[e];                 d = e / 10; }
  else if (e < E_AA + E_AV)  { mi = 1; const int t = e - E_AA;      s = srcAV[t]; d = t / 15; }
  else                       { mi = 2; const int t = e - E_AA - E_AV; s = srcVV[t]; d = NA + t / 15; }
  float sx, sy, sz, dx_, dy_, dz_;
  load_pos(atom_pos, vox_pos, s, sx, sy, sz);
  load_pos(atom_pos, vox_pos, d, dx_, dy_, dz_);
  const float ex = sx - dx_, ey = sy - dy_, ez = sz - dz_;
  const float dist = sqrtf(ex*ex + ey*ey + ez*ez);
  float acc = b2[mi];
#pragma unroll
  for (int j = 0; j < 8; ++j) {
    float h = dist * w1[mi*8 + j] + b1[mi*8 + j];
    h = (h > 0.0f) ? h : 0.0f;
    acc += h * w2[mi*8 + j];
  }
  eattr[e] = acc;
}

// ---------------------------------------------------------------------------
// Chunked aggregation (r29, passing): one chunk of NE edges from E0 with
// chunk-local (max, sum exp, sum exp*srow).
// ---------------------------------------------------------------------------
template<int NE, int E0, bool IS_ATOM>
__device__ __forceinline__ void agg_chunk(
    int n, int lane,
    const float* __restrict__ sbuf, const float* __restrict__ eattr,
    const int* __restrict__ srcA, const int* __restrict__ srcAV,
    const int* __restrict__ srcVV,
    float dn, float wet, float attv,
    float& mC, float& denC, float& msgC)
{
  int esrc[NE]; float eat[NE];
#pragma unroll
  for (int i = 0; i < NE; ++i) {
    const int e = E0 + i;
    int src, eidx;
    if (IS_ATOM) {
      if (e < 10) { src = srcA[n*10 + e];       eidx = n*10 + e; }
      else        { src = srcAV[n*15 + (e-10)]; eidx = E_AA + n*15 + (e-10); }
    } else {
      const int nv = n - NA;
      src = srcVV[nv*15 + e]; eidx = E_AA + E_AV + nv*15 + e;
    }
    esrc[i] = src;
    eat[i]  = eattr[eidx];
  }
  float srow[NE];
#pragma unroll
  for (int i = 0; i < NE; ++i) srow[i] = sbuf[esrc[i]*HD + lane];
  float escore[NE];
#pragma unroll
  for (int i = 0; i < NE; ++i) {
    float mm = srow[i] + dn + eat[i] * wet;
    mm = (mm >= 0.0f) ? mm : 0.2f * mm;        // leaky_relu(0.2)
    escore[i] = head_sum16_dpp(mm * attv);      // reduce over d within head
  }
  mC = -INFINITY;
#pragma unroll
  for (int i = 0; i < NE; ++i) mC = fmaxf(mC, escore[i]);
  denC = 0.0f; msgC = 0.0f;
#pragma unroll
  for (int i = 0; i < NE; ++i) {
    const float a = __expf(escore[i] - mC);
    denC += a;
    msgC = __fmaf_rn(a, srow[i], msgC);
  }
}

// Per-node aggregation via 2-chunk online softmax (r29, passing).
template<bool IS_ATOM>
__device__ __forceinline__ float agg_node(
    int n, int lane,
    float* __restrict__ x,
    const float* __restrict__ sbuf, const float* __restrict__ dbuf,
    const float* __restrict__ eattr,
    const int* __restrict__ srcA, const int* __restrict__ srcAV,
    const int* __restrict__ srcVV,
    const float* __restrict__ We, const float* __restrict__ att, int l,
    float* __restrict__ snap)
{
  const float wet  = We[l*HD + lane];
  const float attv = att[l*HD + lane];
  const float dn   = dbuf[n*HD + lane];

  float m1, d1, g1, m2, d2, g2;
  if (IS_ATOM) {
    agg_chunk<13, 0, true>(n, lane, sbuf, eattr, srcA, srcAV, srcVV,
                           dn, wet, attv, m1, d1, g1);
    agg_chunk<12, 13, true>(n, lane, sbuf, eattr, srcA, srcAV, srcVV,
                            dn, wet, attv, m2, d2, g2);
  } else {
    agg_chunk<8, 0, false>(n, lane, sbuf, eattr, srcA, srcAV, srcVV,
                           dn, wet, attv, m1, d1, g1);
    agg_chunk<7, 8, false>(n, lane, sbuf, eattr, srcA, srcAV, srcVV,
                           dn, wet, attv, m2, d2, g2);
  }
  const float m  = fmaxf(m1, m2);
  const float s1 = __expf(m1 - m);
  const float s2 = __expf(m2 - m);
  const float den = __fmaf_rn(d1, s1, d2 * s2);
  const float msg = __fmaf_rn(g1, s1, g2 * s2) / den;

  float xv = x[n*HD + lane] + msg;
  xv = (xv > 0.0f) ? xv : 0.0f;
  x[n*HD + lane] = xv;
  if (!IS_ATOM && snap != nullptr) snap[(n - NA)*HD + lane] = xv;
  return xv;
}

// ---------------------------------------------------------------------------
// Fused layer (r29 arithmetic): 4 nodes/block agg (2-chunk online softmax),
// LN(l+1) + j-sliced s/d projection; hn exchange transposed ([HD][4]).
// r32: __launch_bounds__(256, 6) — request 6 waves/SIMD (VGPR cap 85) to
// raise occupancy 16 -> 24 waves/CU for the latency-bound gathers. Spill,
// if any, cannot change FP results.
// ---------------------------------------------------------------------------
__global__ __launch_bounds__(256, 6) void layer_kernel(
    float* __restrict__ x,
    const float* __restrict__ sbuf_in, float* __restrict__ dbuf,
    float* __restrict__ sbuf_out,
    const float* __restrict__ eattr,
    const int* __restrict__ srcA, const int* __restrict__ srcAV,
    const int* __restrict__ srcVV,
    const float* __restrict__ We, const float* __restrict__ att,
    const float* __restrict__ ln_g, const float* __restrict__ ln_b,
    const float* __restrict__ Ws, const float* __restrict__ Wd,
    int l, float* __restrict__ snap, int do_next)
{
  const int wid = threadIdx.x >> 6, lane = threadIdx.x & 63;
  const int n = blockIdx.x * 4 + wid;       // blocks are node-type homogeneous
  __shared__ float hn_sh[HD][4];            // transposed: [j][node]
  __shared__ float part[4][4][2][HD];

  float xv;
  if (n < NA) {
    if (!do_next) return;                    // whole block returns uniformly
    xv = agg_node<true>(n, lane, x, sbuf_in, dbuf, eattr,
                        srcA, srcAV, srcVV, We, att, l, nullptr);
  } else {
    xv = agg_node<false>(n, lane, x, sbuf_in, dbuf, eattr,
                         srcA, srcAV, srcVV, We, att, l, snap);
  }
  if (!do_next) return;

  // LayerNorm for layer l+1 (DPP wave sums)
  const int ln = l + 1;
  const float mean = wave_sum64_dpp(xv) * (1.0f/64.0f);
  const float cc   = xv - mean;
  const float var  = wave_sum64_dpp(cc*cc) * (1.0f/64.0f);
  const float hn   = cc * rsqrtf(var + EPS) * ln_g[ln*HD + lane] + ln_b[ln*HD + lane];
  hn_sh[lane][wid] = hn;
  __syncthreads();

  // j-sliced projection: wave wid covers j in [wid*16, wid*16+16) for 4 nodes
  const float* wsp = Ws + (size_t)ln*HD*HD;
  const float* wdp = Wd + (size_t)ln*HD*HD;
  float as0=0.f, as1=0.f, as2=0.f, as3=0.f;
  float ad0=0.f, ad1=0.f, ad2=0.f, ad3=0.f;
#pragma unroll
  for (int jj = 0; jj < 16; ++jj) {
    const int j = wid*16 + jj;
    const float wvs = wsp[j*HD + lane];
    const float wvd = wdp[j*HD + lane];
    const float4 h = *(const float4*)&hn_sh[j][0];   // one ds_read_b128
    as0 += h.x*wvs; ad0 += h.x*wvd;
    as1 += h.y*wvs; ad1 += h.y*wvd;
    as2 += h.z*wvs; ad2 += h.z*wvd;
    as3 += h.w*wvs; ad3 += h.w*wvd;
  }
  part[wid][0][0][lane] = as0; part[wid][0][1][lane] = ad0;
  part[wid][1][0][lane] = as1; part[wid][1][1][lane] = ad1;
  part[wid][2][0][lane] = as2; part[wid][2][1][lane] = ad2;
  part[wid][3][0][lane] = as3; part[wid][3][1][lane] = ad3;
  __syncthreads();

  const float accs = ((part[0][wid][0][lane] + part[1][wid][0][lane])
                    + (part[2][wid][0][lane] + part[3][wid][0][lane]));
  const float accd = ((part[0][wid][1][lane] + part[1][wid][1][lane])
                    + (part[2][wid][1][lane] + part[3][wid][1][lane]));
  sbuf_out[n*HD + lane] = accs;
  dbuf[n*HD + lane]     = accd;
}

// ---------------------------------------------------------------------------
// Output head: 4 vox nodes/block, j-sliced matmuls amortize weight loads 4x.
// ---------------------------------------------------------------------------
__global__ __launch_bounds__(256) void head_kernel(
    const float* __restrict__ snaps,
    const float* __restrict__ Wo1, const float* __restrict__ bo1,
    const float* __restrict__ Wo2, const float* __restrict__ bo2,
    float* __restrict__ out)
{
  const int wid = threadIdx.x >> 6, lane = threadIdx.x & 63;
  const int n = blockIdx.x * 4 + wid;
  __shared__ float cat[4][7*HD];
  __shared__ float part[4][4][HD];
  __shared__ float o1[4][HD];

#pragma unroll
  for (int c = 0; c < 7; ++c)
    cat[wid][c*HD + lane] = snaps[(size_t)c*NV*HD + n*HD + lane];
  __syncthreads();

  float a0=0.f, a1=0.f, a2=0.f, a3=0.f;
  for (int jj = 0; jj < 112; ++jj) {
    const int j = wid*112 + jj;
    const float w = Wo1[j*HD + lane];
    a0 += cat[0][j]*w; a1 += cat[1][j]*w;
    a2 += cat[2][j]*w; a3 += cat[3][j]*w;
  }
  part[wid][0][lane] = a0; part[wid][1][lane] = a1;
  part[wid][2][lane] = a2; part[wid][3][lane] = a3;
  __syncthreads();

  float acc = bo1[lane] + ((part[0][wid][lane] + part[1][wid][lane])
                         + (part[2][wid][lane] + part[3][wid][lane]));
  acc = fmaxf(acc, 0.0f);
  o1[wid][lane] = acc;
  __syncthreads();

  float b0=0.f, b1=0.f, b2=0.f, b3=0.f;
#pragma unroll
  for (int jj = 0; jj < 16; ++jj) {
    const int j = wid*16 + jj;
    const float w = Wo2[j*HD + lane];
    b0 += o1[0][j]*w; b1 += o1[1][j]*w;
    b2 += o1[2][j]*w; b3 += o1[3][j]*w;
  }
  __syncthreads();                       // part reuse
  part[wid][0][lane] = b0; part[wid][1][lane] = b1;
  part[wid][2][lane] = b2; part[wid][3][lane] = b3;
  __syncthreads();

  const float acc2 = bo2[lane] + ((part[0][wid][lane] + part[1][wid][lane])
                                + (part[2][wid][lane] + part[3][wid][lane]));
  out[n*HD + lane] = acc2;
}

__global__ __launch_bounds__(256) void copy_pos_kernel(
    const float* __restrict__ vp, float* __restrict__ out)
{
  const int i = blockIdx.x * 256 + threadIdx.x;
  if (i < NV*3) out[ENC_SIZE + i] = vp[i];
}

// ---------------------------------------------------------------------------
extern "C" void kernel_launch(void* const* d_in, const int* in_sizes, int n_in,
                              void* d_out, int out_size, void* d_ws, size_t ws_size,
                              hipStream_t stream)
{
  const float* atom_x    = (const float*)d_in[0];
  const float* atom_pos  = (const float*)d_in[1];
  const float* vox_x     = (const float*)d_in[2];
  const float* vox_pos   = (const float*)d_in[3];
  const float* W_atom_in = (const float*)d_in[4];
  const float* b_atom_in = (const float*)d_in[5];
  const float* W_vox_in  = (const float*)d_in[6];
  const float* b_vox_in  = (const float*)d_in[7];
  const float* emlp_w1   = (const float*)d_in[8];
  const float* emlp_b1   = (const float*)d_in[9];
  const float* emlp_w2   = (const float*)d_in[10];
  const float* emlp_b2   = (const float*)d_in[11];
  const float* ln_g      = (const float*)d_in[12];
  const float* ln_b      = (const float*)d_in[13];
  const float* Ws        = (const float*)d_in[14];
  const float* Wd        = (const float*)d_in[15];
  const float* We        = (const float*)d_in[16];
  const float* att       = (const float*)d_in[17];
  const float* Wo1       = (const float*)d_in[18];
  const float* bo1       = (const float*)d_in[19];
  const float* Wo2       = (const float*)d_in[20];
  const float* bo2       = (const float*)d_in[21];
  float* out = (float*)d_out;

  // workspace layout (floats), ~21.8 MB
  float* ws    = (float*)d_ws;
  float* x     = ws;                          // [NN][HD]
  float* sA    = x  + (size_t)NN*HD;          // [NN][HD] sbuf ping
  float* sB    = sA + (size_t)NN*HD;          // [NN][HD] sbuf pong
  float* dbuf  = sB + (size_t)NN*HD;          // [NN][HD]
  float* eattr = dbuf + (size_t)NN*HD;        // [E_TOT]
  float* snaps = eattr + E_TOT;               // [7][NV][HD]
  int*   srcA  = (int*)(snaps + (size_t)7*NV*HD);
  int*   srcAV = srcA  + E_AA;
  int*   srcVV = srcAV + E_AV;
  float4* apk  = (float4*)(srcVV + E_VV);     // [NA_PAD] packed atoms
  float4* vpk  = apk + NA_PAD;                // [NV_PAD] packed voxels

  // 1. pack candidates, then merged kNN (dbuf-staged) + init co-resident
  pack_kernel<<<(NA_PAD + NV_PAD + 255)/256, 256, 0, stream>>>(
      atom_pos, vox_pos, apk, vpk);
  knn_all_kernel<<<KNN_BLOCKS + INIT_BLOCKS, 512, 2*KNN_TILE*sizeof(float4), stream>>>(
      atom_pos, vox_pos, apk, vpk, srcA, srcAV, srcVV,
      atom_x, vox_x, W_atom_in, b_atom_in, W_vox_in, b_vox_in,
      ln_g, ln_b, Ws, Wd, x, snaps, sA, dbuf);
  // 2. edge attributes
  edge_attr_kernel<<<(E_TOT + 255)/256, 256, 0, stream>>>(
      atom_pos, vox_pos, srcA, srcAV, srcVV,
      emlp_w1, emlp_b1, emlp_w2, emlp_b2, eattr);
  // 3. 12 fused GAT layers (per-layer dispatch keeps L2 warm across layers)
  for (int l = 0; l < NLAYER; ++l) {
    float* s_in  = (l & 1) ? sB : sA;
    float* s_out = (l & 1) ? sA : sB;
    float* snap  = (l & 1) ? (snaps + (size_t)(l/2 + 1)*NV*HD) : nullptr;
    layer_kernel<<<NGRP, 256, 0, stream>>>(x, s_in, dbuf, s_out, eattr,
                                           srcA, srcAV, srcVV, We, att,
                                           ln_g, ln_b, Ws, Wd, l, snap,
                                           (l < NLAYER-1) ? 1 : 0);
  }
  // 4. output head + vox_pos passthrough
  head_kernel<<<NV/4, 256, 0, stream>>>(snaps, Wo1, bo1, Wo2, bo2, out);
  copy_pos_kernel<<<(NV*3 + 255)/256, 256, 0, stream>>>(vox_pos, out);
}

// Round 33
// 327.520 us; speedup vs baseline: 1.0083x; 1.0083x over previous
//
#include <hip/hip_runtime.h>
#include <math.h>

#define NA 8000
#define NV 4000
#define NN 12000
#define NA_PAD 8192
#define NV_PAD 4096
#define KNN_TILE 1024
#define FEAT 32
#define HD 64
#define NLAYER 12
#define E_AA 80000
#define E_AV 120000
#define E_VV 60000
#define E_TOT 260000
#define ENC_SIZE (NV * HD)
#define EPS 1e-5f
#define NGRP (NN/4)
#define KNN_BLOCKS (NA/8 + NA/8 + NV/8)   // 2500
#define INIT_BLOCKS (NN/8)                 // 1500

__device__ __forceinline__ float wave_sum64(float v) {
#pragma unroll
  for (int off = 1; off < 64; off <<= 1) v += __shfl_xor(v, off);
  return v;
}

// DPP butterfly helpers: pure VALU (v_add_f32_dpp), no DS pipe.
__device__ __forceinline__ float dpp_step(float v, const int ctrl) {
  int p;
  switch (ctrl) {
    case 0xB1:  p = __builtin_amdgcn_update_dpp(0, __float_as_int(v), 0xB1,  0xF, 0xF, true); break;
    case 0x4E:  p = __builtin_amdgcn_update_dpp(0, __float_as_int(v), 0x4E,  0xF, 0xF, true); break;
    case 0x141: p = __builtin_amdgcn_update_dpp(0, __float_as_int(v), 0x141, 0xF, 0xF, true); break;
    default:    p = __builtin_amdgcn_update_dpp(0, __float_as_int(v), 0x140, 0xF, 0xF, true); break;
  }
  return v + __int_as_float(p);
}

__device__ __forceinline__ float head_sum16_dpp(float v) {
  v = dpp_step(v, 0xB1);
  v = dpp_step(v, 0x4E);
  v = dpp_step(v, 0x141);
  v = dpp_step(v, 0x140);
  return v;
}

__device__ __forceinline__ float wave_sum64_dpp(float v) {
  v = head_sum16_dpp(v);
  v += __shfl_xor(v, 16);
  v += __shfl_xor(v, 32);
  return v;
}

// DPP wave_shr:1 (ctrl 0x138): pure-VALU __shfl_up(x,1); lane-0 shifted
// values are dead in the insert (pS forced to 1). (r27, passing)
__device__ __forceinline__ float dpp_shr1_f(float v) {
  const int p = __builtin_amdgcn_update_dpp(0, __float_as_int(v), 0x138, 0xF, 0xF, true);
  return __int_as_float(p);
}
__device__ __forceinline__ int dpp_shr1_i(int v) {
  return __builtin_amdgcn_update_dpp(0, v, 0x138, 0xF, 0xF, true);
}

// ---------------------------------------------------------------------------
// Pack candidate positions as [x, y, z, |c|^2] float4, padded with cc=+INF.
// (FROZEN)
// ---------------------------------------------------------------------------
__global__ __launch_bounds__(256) void pack_kernel(
    const float* __restrict__ apos, const float* __restrict__ vpos,
    float4* __restrict__ apk, float4* __restrict__ vpk)
{
  const int i = blockIdx.x * 256 + threadIdx.x;
  if (i < NA_PAD) {
    float4 r;
    if (i < NA) {
      const float cx = apos[i*3+0], cy = apos[i*3+1], cz = apos[i*3+2];
      r = make_float4(cx, cy, cz, (cx*cx + cy*cy) + cz*cz);
    } else r = make_float4(0.f, 0.f, 0.f, INFINITY);
    apk[i] = r;
  } else {
    const int j = i - NA_PAD;
    if (j < NV_PAD) {
      float4 r;
      if (j < NV) {
        const float cx = vpos[j*3+0], cy = vpos[j*3+1], cz = vpos[j*3+2];
        r = make_float4(cx, cy, cz, (cx*cx + cy*cy) + cz*cz);
      } else r = make_float4(0.f, 0.f, 0.f, INFINITY);
      vpk[j] = r;
    }
  }
}

// ---------------------------------------------------------------------------
// Batched brute-force kNN (r26-r28, passing, FROZEN): pinned d2, DPP insert,
// double-buffered staging, ONE query per wave.
// ---------------------------------------------------------------------------
#define KNN_INS(D2, JB)                                                \
  {                                                                    \
    unsigned long long m = __ballot((D2) < thrD);                      \
    if (m) {                                                           \
      do {                                                             \
        const int sl = __ffsll(m) - 1;                                 \
        m &= (m - 1ULL);                                               \
        const float v  = __shfl((D2), sl);                             \
        const int   vi = (JB) + sl;                                    \
        const bool stay = (eD < v) || (eD == v && eI < vi);            \
        const float pD = dpp_shr1_f(eD);                               \
        const int   pI = dpp_shr1_i(eI);                               \
        int pS = dpp_shr1_i(stay ? 1 : 0);                             \
        if (lane == 0) pS = 1;                                         \
        eD = stay ? eD : (pS ? v  : pD);                               \
        eI = stay ? eI : (pS ? vi : pI);                               \
      } while (m);                                                     \
      thrD = __shfl(eD, K-1);                                          \
    }                                                                  \
  }

template<int K, int NC_PAD>
__device__ __attribute__((noinline)) void knn_body(
    const float* __restrict__ qpos, const float4* __restrict__ cpk,
    int c_off, int* __restrict__ out_src, int qblock)
{
  extern __shared__ float4 tile[];            // [2][KNN_TILE]
  const int tid  = threadIdx.x;
  const int wid  = tid >> 6, lane = tid & 63;
  const int q    = qblock * 8 + wid;
  const float qx = qpos[q*3+0], qy = qpos[q*3+1], qz = qpos[q*3+2];
  float qt = __fmul_rn(qx, qx);
  qt = __fmaf_rn(qy, qy, qt);
  const float qq = __fmaf_rn(qz, qz, qt);     // pinned (r23-verified seq)

  float eD = INFINITY; int eI = 0x7fffffff;   // this lane's entry of the list
  float thrD = INFINITY;                       // K-th best (broadcast)

  // prologue: stage tile 0 into buffer 0
#pragma unroll
  for (int s = 0; s < KNN_TILE/512; ++s)
    tile[s*512 + tid] = cpk[s*512 + tid];
  __syncthreads();

  int cur = 0;
  for (int t0 = 0; t0 < NC_PAD; t0 += KNN_TILE) {
    const int t1 = t0 + KNN_TILE;
    if (t1 < NC_PAD) {                         // stage next tile into other buf
#pragma unroll
      for (int s = 0; s < KNN_TILE/512; ++s)
        tile[(cur^1)*KNN_TILE + s*512 + tid] = cpk[t1 + s*512 + tid];
    }
    const float4* tb = tile + cur*KNN_TILE;
#pragma unroll
    for (int it = 0; it < KNN_TILE/256; ++it) {
      const int b = it*256;
      const float4 c0 = tb[b +   0 + lane];
      const float4 c1 = tb[b +  64 + lane];
      const float4 c2 = tb[b + 128 + lane];
      const float4 c3 = tb[b + 192 + lane];
      float u0 = __fmul_rn(qx, c0.x); u0 = __fmaf_rn(qy, c0.y, u0);
      const float dot0 = __fmaf_rn(qz, c0.z, u0);
      const float d20  = __fadd_rn(__fmaf_rn(-2.0f, dot0, qq), c0.w);
      float u1 = __fmul_rn(qx, c1.x); u1 = __fmaf_rn(qy, c1.y, u1);
      const float dot1 = __fmaf_rn(qz, c1.z, u1);
      const float d21  = __fadd_rn(__fmaf_rn(-2.0f, dot1, qq), c1.w);
      float u2 = __fmul_rn(qx, c2.x); u2 = __fmaf_rn(qy, c2.y, u2);
      const float dot2 = __fmaf_rn(qz, c2.z, u2);
      const float d22  = __fadd_rn(__fmaf_rn(-2.0f, dot2, qq), c2.w);
      float u3 = __fmul_rn(qx, c3.x); u3 = __fmaf_rn(qy, c3.y, u3);
      const float dot3 = __fmaf_rn(qz, c3.z, u3);
      const float d23  = __fadd_rn(__fmaf_rn(-2.0f, dot3, qq), c3.w);
      const float dmin = fminf(fminf(d20, d21), fminf(d22, d23));
      if (__ballot(dmin < thrD)) {             // no lane qualifies -> no insert
        KNN_INS(d20, t0 + b +   0)
        KNN_INS(d21, t0 + b +  64)
        KNN_INS(d22, t0 + b + 128)
        KNN_INS(d23, t0 + b + 192)
      }
    }
    __syncthreads();                           // next tile staged, cur consumed
    cur ^= 1;
  }
  if (lane < K) out_src[q*K + lane] = eI + c_off;
}

// ---------------------------------------------------------------------------
// LayerNorm + s/d projection, single-wave version (used by init branch).
// ---------------------------------------------------------------------------
__device__ __forceinline__ void ln_sd(
    float v, int node, int lane, int l,
    const float* __restrict__ ln_g, const float* __restrict__ ln_b,
    const float* __restrict__ Ws, const float* __restrict__ Wd,
    float* __restrict__ sbuf, float* __restrict__ dbuf)
{
  const float m = wave_sum64_dpp(v) * (1.0f/64.0f);
  const float c = v - m;
  const float var = wave_sum64_dpp(c*c) * (1.0f/64.0f);
  const float hn = c * rsqrtf(var + EPS) * ln_g[l*HD + lane] + ln_b[l*HD + lane];
  const float* ws = Ws + (size_t)l*HD*HD;
  const float* wd = Wd + (size_t)l*HD*HD;
  float accs = 0.0f, accd = 0.0f;
#pragma unroll
  for (int j = 0; j < HD; ++j) {
    const float hj = __shfl(hn, j);
    accs += hj * ws[j*HD + lane];
    accd += hj * wd[j*HD + lane];
  }
  sbuf[node*HD + lane] = accs;
  dbuf[node*HD + lane] = accd;
}

// init work for one node (verbatim init arithmetic; one wave per node).
__device__ __forceinline__ void init_node(
    int node, int lane,
    const float* __restrict__ atom_x, const float* __restrict__ vox_x,
    const float* __restrict__ Wa, const float* __restrict__ ba,
    const float* __restrict__ Wv, const float* __restrict__ bv,
    const float* __restrict__ ln_g, const float* __restrict__ ln_b,
    const float* __restrict__ Ws, const float* __restrict__ Wd,
    float* __restrict__ x, float* __restrict__ snap0,
    float* __restrict__ sbuf, float* __restrict__ dbuf)
{
  const float* in; const float* W; const float* b;
  if (node < NA) { in = atom_x + node*FEAT;     W = Wa; b = ba; }
  else           { in = vox_x + (node-NA)*FEAT; W = Wv; b = bv; }
  float acc = b[lane];
#pragma unroll
  for (int j = 0; j < FEAT; ++j) acc += in[j] * W[j*HD + lane];
  x[node*HD + lane] = acc;
  if (node >= NA) snap0[(node-NA)*HD + lane] = acc;
  ln_sd(acc, node, lane, 0, ln_g, ln_b, Ws, Wd, sbuf, dbuf);
}

// Merged dispatcher: 3 kNN scans + init (independent work) co-resident.
__global__ __launch_bounds__(512) void knn_all_kernel(
    const float* __restrict__ apos, const float* __restrict__ vpos,
    const float4* __restrict__ apk, const float4* __restrict__ vpk,
    int* __restrict__ srcA, int* __restrict__ srcAV, int* __restrict__ srcVV,
    const float* __restrict__ atom_x, const float* __restrict__ vox_x,
    const float* __restrict__ Wa, const float* __restrict__ ba,
    const float* __restrict__ Wv, const float* __restrict__ bv,
    const float* __restrict__ ln_g, const float* __restrict__ ln_b,
    const float* __restrict__ Ws, const float* __restrict__ Wd,
    float* __restrict__ x, float* __restrict__ snap0,
    float* __restrict__ sbuf0, float* __restrict__ dbuf)
{
  const int b = blockIdx.x;                   // block-uniform branch
  const int wid = threadIdx.x >> 6, lane = threadIdx.x & 63;
  if (b < NA/8)
    knn_body<10, NA_PAD>(apos, apk, 0,  srcA,  b);
  else if (b < 2*(NA/8))
    knn_body<15, NV_PAD>(apos, vpk, NA, srcAV, b - NA/8);
  else if (b < KNN_BLOCKS)
    knn_body<15, NV_PAD>(vpos, vpk, NA, srcVV, b - 2*(NA/8));
  else {
    const int node = (b - KNN_BLOCKS)*8 + wid;   // 1500 blocks x 8 = NN
    init_node(node, lane, atom_x, vox_x, Wa, ba, Wv, bv,
              ln_g, ln_b, Ws, Wd, x, snap0, sbuf0, dbuf);
  }
}

// ---------------------------------------------------------------------------
// Edge attribute MLP.
// ---------------------------------------------------------------------------
__device__ __forceinline__ void load_pos(const float* ap, const float* vp,
                                         int i, float& px, float& py, float& pz)
{
  const float* p = (i < NA) ? (ap + i*3) : (vp + (i - NA)*3);
  px = p[0]; py = p[1]; pz = p[2];
}

__global__ __launch_bounds__(256) void edge_attr_kernel(
    const float* __restrict__ atom_pos, const float* __restrict__ vox_pos,
    const int* __restrict__ srcA, const int* __restrict__ srcAV,
    const int* __restrict__ srcVV,
    const float* __restrict__ w1, const float* __restrict__ b1,
    const float* __restrict__ w2, const float* __restrict__ b2,
    float* __restrict__ eattr)
{
  const int e = blockIdx.x * 256 + threadIdx.x;
  if (e >= E_TOT) return;
  int s, d, mi;
  if (e < E_AA)              { mi = 0; s = srcA[e];                 d = e / 10; }
  else if (e < E_AA + E_AV)  { mi = 1; const int t = e - E_AA;      s = srcAV[t]; d = t / 15; }
  else                       { mi = 2; const int t = e - E_AA - E_AV; s = srcVV[t]; d = NA + t / 15; }
  float sx, sy, sz, dx_, dy_, dz_;
  load_pos(atom_pos, vox_pos, s, sx, sy, sz);
  load_pos(atom_pos, vox_pos, d, dx_, dy_, dz_);
  const float ex = sx - dx_, ey = sy - dy_, ez = sz - dz_;
  const float dist = sqrtf(ex*ex + ey*ey + ez*ez);
  float acc = b2[mi];
#pragma unroll
  for (int j = 0; j < 8; ++j) {
    float h = dist * w1[mi*8 + j] + b1[mi*8 + j];
    h = (h > 0.0f) ? h : 0.0f;
    acc += h * w2[mi*8 + j];
  }
  eattr[e] = acc;
}

// ---------------------------------------------------------------------------
// Chunked aggregation (r29, passing): one chunk of NE edges from E0 with
// chunk-local (max, sum exp, sum exp*srow).
// ---------------------------------------------------------------------------
template<int NE, int E0, bool IS_ATOM>
__device__ __forceinline__ void agg_chunk(
    int n, int lane,
    const float* __restrict__ sbuf, const float* __restrict__ eattr,
    const int* __restrict__ srcA, const int* __restrict__ srcAV,
    const int* __restrict__ srcVV,
    float dn, float wet, float attv,
    float& mC, float& denC, float& msgC)
{
  int esrc[NE]; float eat[NE];
#pragma unroll
  for (int i = 0; i < NE; ++i) {
    const int e = E0 + i;
    int src, eidx;
    if (IS_ATOM) {
      if (e < 10) { src = srcA[n*10 + e];       eidx = n*10 + e; }
      else        { src = srcAV[n*15 + (e-10)]; eidx = E_AA + n*15 + (e-10); }
    } else {
      const int nv = n - NA;
      src = srcVV[nv*15 + e]; eidx = E_AA + E_AV + nv*15 + e;
    }
    esrc[i] = src;
    eat[i]  = eattr[eidx];
  }
  float srow[NE];
#pragma unroll
  for (int i = 0; i < NE; ++i) srow[i] = sbuf[esrc[i]*HD + lane];
  float escore[NE];
#pragma unroll
  for (int i = 0; i < NE; ++i) {
    float mm = srow[i] + dn + eat[i] * wet;
    mm = (mm >= 0.0f) ? mm : 0.2f * mm;        // leaky_relu(0.2)
    escore[i] = head_sum16_dpp(mm * attv);      // reduce over d within head
  }
  mC = -INFINITY;
#pragma unroll
  for (int i = 0; i < NE; ++i) mC = fmaxf(mC, escore[i]);
  denC = 0.0f; msgC = 0.0f;
#pragma unroll
  for (int i = 0; i < NE; ++i) {
    const float a = __expf(escore[i] - mC);
    denC += a;
    msgC = __fmaf_rn(a, srow[i], msgC);
  }
}

// Per-node aggregation via 2-chunk online softmax (r29, passing).
template<bool IS_ATOM>
__device__ __forceinline__ float agg_node(
    int n, int lane,
    float* __restrict__ x,
    const float* __restrict__ sbuf, const float* __restrict__ dbuf,
    const float* __restrict__ eattr,
    const int* __restrict__ srcA, const int* __restrict__ srcAV,
    const int* __restrict__ srcVV,
    const float* __restrict__ We, const float* __restrict__ att, int l,
    float* __restrict__ snap)
{
  const float wet  = We[l*HD + lane];
  const float attv = att[l*HD + lane];
  const float dn   = dbuf[n*HD + lane];

  float m1, d1, g1, m2, d2, g2;
  if (IS_ATOM) {
    agg_chunk<13, 0, true>(n, lane, sbuf, eattr, srcA, srcAV, srcVV,
                           dn, wet, attv, m1, d1, g1);
    agg_chunk<12, 13, true>(n, lane, sbuf, eattr, srcA, srcAV, srcVV,
                            dn, wet, attv, m2, d2, g2);
  } else {
    agg_chunk<8, 0, false>(n, lane, sbuf, eattr, srcA, srcAV, srcVV,
                           dn, wet, attv, m1, d1, g1);
    agg_chunk<7, 8, false>(n, lane, sbuf, eattr, srcA, srcAV, srcVV,
                           dn, wet, attv, m2, d2, g2);
  }
  const float m  = fmaxf(m1, m2);
  const float s1 = __expf(m1 - m);
  const float s2 = __expf(m2 - m);
  const float den = __fmaf_rn(d1, s1, d2 * s2);
  const float msg = __fmaf_rn(g1, s1, g2 * s2) / den;

  float xv = x[n*HD + lane] + msg;
  xv = (xv > 0.0f) ? xv : 0.0f;
  x[n*HD + lane] = xv;
  if (!IS_ATOM && snap != nullptr) snap[(n - NA)*HD + lane] = xv;
  return xv;
}

// ---------------------------------------------------------------------------
// Fused layer (r29/r31 best-known, FINAL): 4 nodes/block agg (2-chunk online
// softmax), LN(l+1) + j-sliced s/d projection; hn exchange transposed.
// launch_bounds(256,4): natural VGPR ~100-128, 16 waves/CU. r32 probe showed
// (256,6) spills and regresses; r15 showed capping below 4 is neutral.
// ---------------------------------------------------------------------------
__global__ __launch_bounds__(256, 4) void layer_kernel(
    float* __restrict__ x,
    const float* __restrict__ sbuf_in, float* __restrict__ dbuf,
    float* __restrict__ sbuf_out,
    const float* __restrict__ eattr,
    const int* __restrict__ srcA, const int* __restrict__ srcAV,
    const int* __restrict__ srcVV,
    const float* __restrict__ We, const float* __restrict__ att,
    const float* __restrict__ ln_g, const float* __restrict__ ln_b,
    const float* __restrict__ Ws, const float* __restrict__ Wd,
    int l, float* __restrict__ snap, int do_next)
{
  const int wid = threadIdx.x >> 6, lane = threadIdx.x & 63;
  const int n = blockIdx.x * 4 + wid;       // blocks are node-type homogeneous
  __shared__ float hn_sh[HD][4];            // transposed: [j][node]
  __shared__ float part[4][4][2][HD];

  float xv;
  if (n < NA) {
    if (!do_next) return;                    // whole block returns uniformly
    xv = agg_node<true>(n, lane, x, sbuf_in, dbuf, eattr,
                        srcA, srcAV, srcVV, We, att, l, nullptr);
  } else {
    xv = agg_node<false>(n, lane, x, sbuf_in, dbuf, eattr,
                         srcA, srcAV, srcVV, We, att, l, snap);
  }
  if (!do_next) return;

  // LayerNorm for layer l+1 (DPP wave sums)
  const int ln = l + 1;
  const float mean = wave_sum64_dpp(xv) * (1.0f/64.0f);
  const float cc   = xv - mean;
  const float var  = wave_sum64_dpp(cc*cc) * (1.0f/64.0f);
  const float hn   = cc * rsqrtf(var + EPS) * ln_g[ln*HD + lane] + ln_b[ln*HD + lane];
  hn_sh[lane][wid] = hn;
  __syncthreads();

  // j-sliced projection: wave wid covers j in [wid*16, wid*16+16) for 4 nodes
  const float* wsp = Ws + (size_t)ln*HD*HD;
  const float* wdp = Wd + (size_t)ln*HD*HD;
  float as0=0.f, as1=0.f, as2=0.f, as3=0.f;
  float ad0=0.f, ad1=0.f, ad2=0.f, ad3=0.f;
#pragma unroll
  for (int jj = 0; jj < 16; ++jj) {
    const int j = wid*16 + jj;
    const float wvs = wsp[j*HD + lane];
    const float wvd = wdp[j*HD + lane];
    const float4 h = *(const float4*)&hn_sh[j][0];   // one ds_read_b128
    as0 += h.x*wvs; ad0 += h.x*wvd;
    as1 += h.y*wvs; ad1 += h.y*wvd;
    as2 += h.z*wvs; ad2 += h.z*wvd;
    as3 += h.w*wvs; ad3 += h.w*wvd;
  }
  part[wid][0][0][lane] = as0; part[wid][0][1][lane] = ad0;
  part[wid][1][0][lane] = as1; part[wid][1][1][lane] = ad1;
  part[wid][2][0][lane] = as2; part[wid][2][1][lane] = ad2;
  part[wid][3][0][lane] = as3; part[wid][3][1][lane] = ad3;
  __syncthreads();

  const float accs = ((part[0][wid][0][lane] + part[1][wid][0][lane])
                    + (part[2][wid][0][lane] + part[3][wid][0][lane]));
  const float accd = ((part[0][wid][1][lane] + part[1][wid][1][lane])
                    + (part[2][wid][1][lane] + part[3][wid][1][lane]));
  sbuf_out[n*HD + lane] = accs;
  dbuf[n*HD + lane]     = accd;
}

// ---------------------------------------------------------------------------
// Output head: 4 vox nodes/block, j-sliced matmuls amortize weight loads 4x.
// ---------------------------------------------------------------------------
__global__ __launch_bounds__(256) void head_kernel(
    const float* __restrict__ snaps,
    const float* __restrict__ Wo1, const float* __restrict__ bo1,
    const float* __restrict__ Wo2, const float* __restrict__ bo2,
    float* __restrict__ out)
{
  const int wid = threadIdx.x >> 6, lane = threadIdx.x & 63;
  const int n = blockIdx.x * 4 + wid;
  __shared__ float cat[4][7*HD];
  __shared__ float part[4][4][HD];
  __shared__ float o1[4][HD];

#pragma unroll
  for (int c = 0; c < 7; ++c)
    cat[wid][c*HD + lane] = snaps[(size_t)c*NV*HD + n*HD + lane];
  __syncthreads();

  float a0=0.f, a1=0.f, a2=0.f, a3=0.f;
  for (int jj = 0; jj < 112; ++jj) {
    const int j = wid*112 + jj;
    const float w = Wo1[j*HD + lane];
    a0 += cat[0][j]*w; a1 += cat[1][j]*w;
    a2 += cat[2][j]*w; a3 += cat[3][j]*w;
  }
  part[wid][0][lane] = a0; part[wid][1][lane] = a1;
  part[wid][2][lane] = a2; part[wid][3][lane] = a3;
  __syncthreads();

  float acc = bo1[lane] + ((part[0][wid][lane] + part[1][wid][lane])
                         + (part[2][wid][lane] + part[3][wid][lane]));
  acc = fmaxf(acc, 0.0f);
  o1[wid][lane] = acc;
  __syncthreads();

  float b0=0.f, b1=0.f, b2=0.f, b3=0.f;
#pragma unroll
  for (int jj = 0; jj < 16; ++jj) {
    const int j = wid*16 + jj;
    const float w = Wo2[j*HD + lane];
    b0 += o1[0][j]*w; b1 += o1[1][j]*w;
    b2 += o1[2][j]*w; b3 += o1[3][j]*w;
  }
  __syncthreads();                       // part reuse
  part[wid][0][lane] = b0; part[wid][1][lane] = b1;
  part[wid][2][lane] = b2; part[wid][3][lane] = b3;
  __syncthreads();

  const float acc2 = bo2[lane] + ((part[0][wid][lane] + part[1][wid][lane])
                                + (part[2][wid][lane] + part[3][wid][lane]));
  out[n*HD + lane] = acc2;
}

__global__ __launch_bounds__(256) void copy_pos_kernel(
    const float* __restrict__ vp, float* __restrict__ out)
{
  const int i = blockIdx.x * 256 + threadIdx.x;
  if (i < NV*3) out[ENC_SIZE + i] = vp[i];
}

// ---------------------------------------------------------------------------
extern "C" void kernel_launch(void* const* d_in, const int* in_sizes, int n_in,
                              void* d_out, int out_size, void* d_ws, size_t ws_size,
                              hipStream_t stream)
{
  const float* atom_x    = (const float*)d_in[0];
  const float* atom_pos  = (const float*)d_in[1];
  const float* vox_x     = (const float*)d_in[2];
  const float* vox_pos   = (const float*)d_in[3];
  const float* W_atom_in = (const float*)d_in[4];
  const float* b_atom_in = (const float*)d_in[5];
  const float* W_vox_in  = (const float*)d_in[6];
  const float* b_vox_in  = (const float*)d_in[7];
  const float* emlp_w1   = (const float*)d_in[8];
  const float* emlp_b1   = (const float*)d_in[9];
  const float* emlp_w2   = (const float*)d_in[10];
  const float* emlp_b2   = (const float*)d_in[11];
  const float* ln_g      = (const float*)d_in[12];
  const float* ln_b      = (const float*)d_in[13];
  const float* Ws        = (const float*)d_in[14];
  const float* Wd        = (const float*)d_in[15];
  const float* We        = (const float*)d_in[16];
  const float* att       = (const float*)d_in[17];
  const float* Wo1       = (const float*)d_in[18];
  const float* bo1       = (const float*)d_in[19];
  const float* Wo2       = (const float*)d_in[20];
  const float* bo2       = (const float*)d_in[21];
  float* out = (float*)d_out;

  // workspace layout (floats), ~21.8 MB
  float* ws    = (float*)d_ws;
  float* x     = ws;                          // [NN][HD]
  float* sA    = x  + (size_t)NN*HD;          // [NN][HD] sbuf ping
  float* sB    = sA + (size_t)NN*HD;          // [NN][HD] sbuf pong
  float* dbuf  = sB + (size_t)NN*HD;          // [NN][HD]
  float* eattr = dbuf + (size_t)NN*HD;        // [E_TOT]
  float* snaps = eattr + E_TOT;               // [7][NV][HD]
  int*   srcA  = (int*)(snaps + (size_t)7*NV*HD);
  int*   srcAV = srcA  + E_AA;
  int*   srcVV = srcAV + E_AV;
  float4* apk  = (float4*)(srcVV + E_VV);     // [NA_PAD] packed atoms
  float4* vpk  = apk + NA_PAD;                // [NV_PAD] packed voxels

  // 1. pack candidates, then merged kNN (dbuf-staged) + init co-resident
  pack_kernel<<<(NA_PAD + NV_PAD + 255)/256, 256, 0, stream>>>(
      atom_pos, vox_pos, apk, vpk);
  knn_all_kernel<<<KNN_BLOCKS + INIT_BLOCKS, 512, 2*KNN_TILE*sizeof(float4), stream>>>(
      atom_pos, vox_pos, apk, vpk, srcA, srcAV, srcVV,
      atom_x, vox_x, W_atom_in, b_atom_in, W_vox_in, b_vox_in,
      ln_g, ln_b, Ws, Wd, x, snaps, sA, dbuf);
  // 2. edge attributes
  edge_attr_kernel<<<(E_TOT + 255)/256, 256, 0, stream>>>(
      atom_pos, vox_pos, srcA, srcAV, srcVV,
      emlp_w1, emlp_b1, emlp_w2, emlp_b2, eattr);
  // 3. 12 fused GAT layers (per-layer dispatch keeps L2 warm across layers)
  for (int l = 0; l < NLAYER; ++l) {
    float* s_in  = (l & 1) ? sB : sA;
    float* s_out = (l & 1) ? sA : sB;
    float* snap  = (l & 1) ? (snaps + (size_t)(l/2 + 1)*NV*HD) : nullptr;
    layer_kernel<<<NGRP, 256, 0, stream>>>(x, s_in, dbuf, s_out, eattr,
                                           srcA, srcAV, srcVV, We, att,
                                           ln_g, ln_b, Ws, Wd, l, snap,
                                           (l < NLAYER-1) ? 1 : 0);
  }
  // 4. output head + vox_pos passthrough
  head_kernel<<<NV/4, 256, 0, stream>>>(snaps, Wo1, bo1, Wo2, bo2, out);
  copy_pos_kernel<<<(NV*3 + 255)/256, 256, 0, stream>>>(vox_pos, out);
}